// Round 7
// baseline (245.663 us; speedup 1.0000x reference)
//
#include <hip/hip_runtime.h>
#include <math.h>

#define B_  2
#define S_  2048
#define D_  1024
#define H_  16
#define DH_ 64
#define M_  (B_ * S_)   // 4096

typedef _Float16 half_t;
typedef __attribute__((ext_vector_type(8))) _Float16 h8;
typedef __attribute__((ext_vector_type(4))) _Float16 h4;
typedef __attribute__((ext_vector_type(4))) float   f32x4;

#define LOG2E 1.44269504088896f

// async global->LDS, 16 B per lane (lane-contiguous dest, m104/m108)
__device__ __forceinline__ void gll16(const half_t* g, half_t* l) {
    __builtin_amdgcn_global_load_lds(
        (__attribute__((address_space(1))) const void*)g,
        (__attribute__((address_space(3))) void*)l, 16, 0, 0);
}

// ---------------------------------------------------------------------------
// Prepass (fused): blocks 0..2047 convert x fp32->fp16; blocks 2048..3583
// transpose W [k][n] fp32 -> Wt [n][k] fp16 (3 matrices).
// ---------------------------------------------------------------------------
__global__ __launch_bounds__(256) void prep_k(
    const float* __restrict__ x, half_t* __restrict__ xh,
    const float* __restrict__ Wq, const float* __restrict__ Wk,
    const float* __restrict__ Wv, half_t* __restrict__ Wt)
{
    const int bx = blockIdx.x;
    if (bx < 2048) {
        const size_t i = ((size_t)bx * 256 + threadIdx.x) * 8;
        const float4 a = *(const float4*)(x + i);
        const float4 b = *(const float4*)(x + i + 4);
        h8 o;
        o[0] = (half_t)a.x; o[1] = (half_t)a.y; o[2] = (half_t)a.z; o[3] = (half_t)a.w;
        o[4] = (half_t)b.x; o[5] = (half_t)b.y; o[6] = (half_t)b.z; o[7] = (half_t)b.w;
        *(h8*)(xh + i) = o;
    } else {
        const int gb    = bx - 2048;                 // 0..1535
        const int which = gb >> 9;
        const float* __restrict__ W = (which == 0) ? Wq : (which == 1) ? Wk : Wv;
        half_t* __restrict__ T = Wt + (size_t)which * D_ * D_;
        const int gw   = (gb & 511) * 4 + (threadIdx.x >> 6);   // 0..2047
        const int lane = threadIdx.x & 63;
        const int n    = (gw & 15) * 64 + lane;
        const int k0   = (gw >> 4) * 8;
        h8 o;
        #pragma unroll
        for (int t = 0; t < 8; ++t) o[t] = (half_t)W[(size_t)(k0 + t) * D_ + n];
        *(h8*)(T + (size_t)n * D_ + k0) = o;
    }
}

// ---------------------------------------------------------------------------
// Kernel 1: fused QKV projection.  128x128 tile, BK=64, global_load_lds into
// XOR-chunk-swizzled unpadded LDS.  1D grid with XCD-aware swizzle: blocks
// with the same (blockIdx&7) land on the same XCD (dispatch round-robin) and
// share a 4-m-tile band -> A stays L2-resident, W streamed once per XCD.
// Epilogue: Q = tanh-GELU * log2e, K natural, V pre-transposed to Vt[bh][d][s].
// ---------------------------------------------------------------------------
__global__ __launch_bounds__(256) void qkv_gemm_f16(
    const half_t* __restrict__ xh, const half_t* __restrict__ Wt,
    const float* __restrict__ bq, const float* __restrict__ bk,
    const float* __restrict__ bv,
    half_t* __restrict__ Qo, half_t* __restrict__ Ko, half_t* __restrict__ Vt)
{
    const int bi = blockIdx.x;                       // 0..767
    const int mt = (bi & 7) * 4 + ((bi >> 3) & 3);   // 0..31
    const int nt = bi >> 5;                          // 0..23
    const int m0 = mt * 128;
    const int n0g = nt * 128;
    const int which = n0g >> 10;
    const int n0    = n0g & 1023;
    const half_t* __restrict__ Wp  = Wt + (size_t)which * D_ * D_;
    const float* __restrict__ bias = (which == 0) ? bq : (which == 1) ? bk : bv;

    const int tid = threadIdx.x, lane = tid & 63, wave = tid >> 6;
    const int wm = (wave >> 1) * 64, wn = (wave & 1) * 64;
    const int ln = lane & 15, quad = lane >> 4;

    __shared__ __align__(16) half_t As[128 * 64];   // swizzled slots
    __shared__ __align__(16) half_t Bs[128 * 64];

    f32x4 acc[4][4];
    #pragma unroll
    for (int i = 0; i < 4; ++i)
        #pragma unroll
        for (int j = 0; j < 4; ++j) acc[i][j] = (f32x4){0.f, 0.f, 0.f, 0.f};

    for (int k0 = 0; k0 < D_; k0 += 64) {
        __syncthreads();
        #pragma unroll
        for (int l = 0; l < 4; ++l) {
            const int c  = tid + l * 256;
            const int r  = c >> 3, c0 = c & 7;
            const int cs = c0 ^ (r & 7);
            gll16(xh + (size_t)(m0 + r) * D_ + k0 + cs * 8, &As[c * 8]);
            gll16(Wp + (size_t)(n0 + r) * D_ + k0 + cs * 8, &Bs[c * 8]);
        }
        __syncthreads();

        #pragma unroll
        for (int kc = 0; kc < 2; ++kc) {
            h8 af[4], bf[4];
            #pragma unroll
            for (int i = 0; i < 4; ++i) {
                const int r = wm + i * 16 + ln;
                af[i] = *(const h8*)&As[r * 64 + (((kc << 2) + quad) ^ (r & 7)) * 8];
            }
            #pragma unroll
            for (int j = 0; j < 4; ++j) {
                const int r = wn + j * 16 + ln;
                bf[j] = *(const h8*)&Bs[r * 64 + (((kc << 2) + quad) ^ (r & 7)) * 8];
            }
            #pragma unroll
            for (int i = 0; i < 4; ++i)
                #pragma unroll
                for (int j = 0; j < 4; ++j)
                    acc[i][j] = __builtin_amdgcn_mfma_f32_16x16x32_f16(
                        af[i], bf[j], acc[i][j], 0, 0, 0);
        }
    }

    if (which == 2) {
        #pragma unroll
        for (int j = 0; j < 4; ++j) {
            const int col = n0 + wn + j * 16 + ln;
            const int h = col >> 6, d = col & 63;
            const float bb = bias[col];
            #pragma unroll
            for (int i = 0; i < 4; ++i) {
                const int sg = m0 + wm + i * 16 + quad * 4;
                const int b  = sg >> 11, srow = sg & 2047;
                h4 pv;
                #pragma unroll
                for (int r = 0; r < 4; ++r) pv[r] = (half_t)(acc[i][j][r] + bb);
                *(h4*)(Vt + (((size_t)(b * H_ + h) * DH_ + d) * S_ + srow)) = pv;
            }
        }
    } else {
        half_t* __restrict__ out = (which == 0) ? Qo : Ko;
        #pragma unroll
        for (int j = 0; j < 4; ++j) {
            const int col = n0 + wn + j * 16 + ln;
            const float bb = bias[col];
            #pragma unroll
            for (int i = 0; i < 4; ++i) {
                #pragma unroll
                for (int r = 0; r < 4; ++r) {
                    const int row = m0 + wm + i * 16 + quad * 4 + r;
                    float t = acc[i][j][r] + bb;
                    if (which == 0) {
                        const float u = t * fmaf(t * t, 0.0356774081f, 0.7978845608f);
                        const float e = __builtin_amdgcn_exp2f(u * -2.88539008178f);
                        t = t * __builtin_amdgcn_rcpf(1.0f + e) * LOG2E;
                    }
                    out[(size_t)row * D_ + col] = (half_t)t;
                }
            }
        }
    }
}

// ---------------------------------------------------------------------------
// Kernel 2: flash attention, ZERO-barrier k-loop.  128 q-rows per block,
// 4 waves x 32 rows.  K/V/Q MFMA fragments are loaded DIRECTLY from global
// (h8 in exact fragment layout; 64B segments served by L1/L2 — every K/V
// tile is read by all 4 waves and reused by 16 q-blocks).  LDS holds only
// the wave-private P roundtrip (18.4 KB).  No __syncthreads anywhere.
// Logits pre-scaled by log2e (p = 2^x); l via ones-MFMA; conditional rescale.
// XCD swizzle: same-XCD blocks share a 4-bh band -> K/V L2-resident.
// ---------------------------------------------------------------------------
__global__ __launch_bounds__(256) void attn_f16(
    const half_t* __restrict__ Q, const half_t* __restrict__ K,
    const half_t* __restrict__ Vt, float* __restrict__ out)
{
    const int tid  = threadIdx.x;
    const int lane = tid & 63;
    const int wave = tid >> 6;
    const int ln   = lane & 15;
    const int quad = lane >> 4;

    const int bi = blockIdx.x;                      // 0..511
    const int bh = (bi & 7) * 4 + ((bi >> 3) & 3);  // 0..31
    const int q0 = (bi >> 5) * 128;                 // 0..1920
    const int b  = bh >> 4;
    const int h  = bh & 15;

    const half_t* __restrict__ Qb  = Q  + (size_t)b * S_ * D_ + h * DH_;
    const half_t* __restrict__ Kb  = K  + (size_t)b * S_ * D_ + h * DH_;
    const half_t* __restrict__ Vtb = Vt + (size_t)bh * DH_ * S_;

    __shared__ __align__(16) half_t Ps[128][72];    // wave-private 32-row bands

    // ---- Q fragments, direct from global (loaded once) ----
    const int qra = q0 + wave * 32 + ln;
    const h8 qa0 = *(const h8*)(Qb + (size_t)qra * D_ + quad * 8);
    const h8 qa1 = *(const h8*)(Qb + (size_t)qra * D_ + 32 + quad * 8);
    const h8 qc0 = *(const h8*)(Qb + (size_t)(qra + 16) * D_ + quad * 8);
    const h8 qc1 = *(const h8*)(Qb + (size_t)(qra + 16) * D_ + 32 + quad * 8);

    h8 ones8;
    #pragma unroll
    for (int t = 0; t < 8; ++t) ones8[t] = (half_t)1.0f;

    f32x4 Oa[4], Ob[4];
    #pragma unroll
    for (int j = 0; j < 4; ++j) {
        Oa[j] = (f32x4){0.f, 0.f, 0.f, 0.f};
        Ob[j] = (f32x4){0.f, 0.f, 0.f, 0.f};
    }
    f32x4 la = (f32x4){0.f, 0.f, 0.f, 0.f};
    f32x4 lb = (f32x4){0.f, 0.f, 0.f, 0.f};
    float m_a = -INFINITY, m_b = -INFINITY;

    for (int k0 = 0; k0 < S_; k0 += 64) {
        // ---- K fragments direct from global ----
        h8 ka0[4], ka1[4];
        #pragma unroll
        for (int j = 0; j < 4; ++j) {
            const half_t* kp = Kb + (size_t)(k0 + j * 16 + ln) * D_;
            ka0[j] = *(const h8*)(kp + quad * 8);
            ka1[j] = *(const h8*)(kp + 32 + quad * 8);
        }

        // ---- S^T = K Q^T for both q-groups ----
        f32x4 sa[4], sb[4];
        #pragma unroll
        for (int j = 0; j < 4; ++j) {
            f32x4 t = (f32x4){0.f, 0.f, 0.f, 0.f};
            t = __builtin_amdgcn_mfma_f32_16x16x32_f16(ka0[j], qa0, t, 0, 0, 0);
            t = __builtin_amdgcn_mfma_f32_16x16x32_f16(ka1[j], qa1, t, 0, 0, 0);
            sa[j] = t;
            f32x4 u = (f32x4){0.f, 0.f, 0.f, 0.f};
            u = __builtin_amdgcn_mfma_f32_16x16x32_f16(ka0[j], qc0, u, 0, 0, 0);
            u = __builtin_amdgcn_mfma_f32_16x16x32_f16(ka1[j], qc1, u, 0, 0, 0);
            sb[j] = u;
        }

        // ---- V fragments direct from global (latency hidden by softmax) ----
        h8 vb0[4], vb1[4];
        #pragma unroll
        for (int j = 0; j < 4; ++j) {
            const half_t* vp = Vtb + (size_t)(j * 16 + ln) * S_ + k0;
            vb0[j] = *(const h8*)(vp + quad * 8);
            vb1[j] = *(const h8*)(vp + 32 + quad * 8);
        }

        // ---- online softmax (log2 domain), conditional rescale ----
        float mxa = sa[0][0], mxb = sb[0][0];
        #pragma unroll
        for (int j = 0; j < 4; ++j)
            #pragma unroll
            for (int r = 0; r < 4; ++r) {
                mxa = fmaxf(mxa, sa[j][r]);
                mxb = fmaxf(mxb, sb[j][r]);
            }
        mxa = fmaxf(mxa, __shfl_xor(mxa, 16, 64));
        mxa = fmaxf(mxa, __shfl_xor(mxa, 32, 64));
        mxb = fmaxf(mxb, __shfl_xor(mxb, 16, 64));
        mxb = fmaxf(mxb, __shfl_xor(mxb, 32, 64));

        if (__ballot(mxa > m_a || mxb > m_b)) {
            const float mna = fmaxf(m_a, mxa);
            const float mnb = fmaxf(m_b, mxb);
            const float ala = __builtin_amdgcn_exp2f(m_a - mna);
            const float alb = __builtin_amdgcn_exp2f(m_b - mnb);
            m_a = mna; m_b = mnb;
            float ra[4], rb[4];
            #pragma unroll
            for (int r = 0; r < 4; ++r) {
                ra[r] = __shfl(ala, quad * 4 + r, 64);
                rb[r] = __shfl(alb, quad * 4 + r, 64);
            }
            #pragma unroll
            for (int r = 0; r < 4; ++r) {
                la[r] *= ra[r]; lb[r] *= rb[r];
                #pragma unroll
                for (int j = 0; j < 4; ++j) { Oa[j][r] *= ra[r]; Ob[j][r] *= rb[r]; }
            }
        }

        // p = 2^(s - m), h4-packed b64 writes into wave-private bands
        #pragma unroll
        for (int j = 0; j < 4; ++j) {
            h4 pva, pvb;
            #pragma unroll
            for (int r = 0; r < 4; ++r) {
                pva[r] = (half_t)__builtin_amdgcn_exp2f(sa[j][r] - m_a);
                pvb[r] = (half_t)__builtin_amdgcn_exp2f(sb[j][r] - m_b);
            }
            *(h4*)&Ps[wave * 32 + ln][j * 16 + quad * 4]      = pva;
            *(h4*)&Ps[wave * 32 + 16 + ln][j * 16 + quad * 4] = pvb;
        }

        // ---- O += P V, l += P 1 ----
        const h8 pa0 = *(const h8*)&Ps[wave * 32 + ln][quad * 8];
        const h8 pa1 = *(const h8*)&Ps[wave * 32 + ln][32 + quad * 8];
        const h8 pb0 = *(const h8*)&Ps[wave * 32 + 16 + ln][quad * 8];
        const h8 pb1 = *(const h8*)&Ps[wave * 32 + 16 + ln][32 + quad * 8];
        #pragma unroll
        for (int j = 0; j < 4; ++j) {
            Oa[j] = __builtin_amdgcn_mfma_f32_16x16x32_f16(pa0, vb0[j], Oa[j], 0, 0, 0);
            Oa[j] = __builtin_amdgcn_mfma_f32_16x16x32_f16(pa1, vb1[j], Oa[j], 0, 0, 0);
            Ob[j] = __builtin_amdgcn_mfma_f32_16x16x32_f16(pb0, vb0[j], Ob[j], 0, 0, 0);
            Ob[j] = __builtin_amdgcn_mfma_f32_16x16x32_f16(pb1, vb1[j], Ob[j], 0, 0, 0);
        }
        la = __builtin_amdgcn_mfma_f32_16x16x32_f16(pa0, ones8, la, 0, 0, 0);
        la = __builtin_amdgcn_mfma_f32_16x16x32_f16(pa1, ones8, la, 0, 0, 0);
        lb = __builtin_amdgcn_mfma_f32_16x16x32_f16(pb0, ones8, lb, 0, 0, 0);
        lb = __builtin_amdgcn_mfma_f32_16x16x32_f16(pb1, ones8, lb, 0, 0, 0);
    }

    // ---- epilogue: normalize, store fp32 ----
    #pragma unroll
    for (int r = 0; r < 4; ++r) {
        const float iva = 1.0f / la[r];
        const float ivb = 1.0f / lb[r];
        const int rowa = q0 + wave * 32 + quad * 4 + r;
        const int rowb = rowa + 16;
        #pragma unroll
        for (int j = 0; j < 4; ++j) {
            out[((size_t)b * S_ + rowa) * D_ + h * DH_ + j * 16 + ln] = Oa[j][r] * iva;
            out[((size_t)b * S_ + rowb) * D_ + h * DH_ + j * 16 + ln] = Ob[j][r] * ivb;
        }
    }
}

// ---------------------------------------------------------------------------
extern "C" void kernel_launch(void* const* d_in, const int* in_sizes, int n_in,
                              void* d_out, int out_size, void* d_ws, size_t ws_size,
                              hipStream_t stream) {
    const float* x  = (const float*)d_in[0];
    const float* Wq = (const float*)d_in[1];
    const float* bq = (const float*)d_in[2];
    const float* Wk = (const float*)d_in[3];
    const float* bk = (const float*)d_in[4];
    const float* Wv = (const float*)d_in[5];
    const float* bv = (const float*)d_in[6];
    float* out = (float*)d_out;

    const size_t nmd = (size_t)M_ * D_;   // 4M
    const size_t ndd = (size_t)D_ * D_;   // 1M
    half_t* xh  = (half_t*)d_ws;          // 4M halves
    half_t* Wt  = xh + nmd;               // 3M
    half_t* Qh  = Wt + 3 * ndd;           // 4M
    half_t* Kh  = Qh + nmd;               // 4M
    half_t* Vtw = Kh + nmd;               // 4M  (38 MB total)

    prep_k<<<2048 + 1536, 256, 0, stream>>>(x, xh, Wq, Wk, Wv, Wt);
    qkv_gemm_f16<<<768, 256, 0, stream>>>(xh, Wt, bq, bk, bv, Qh, Kh, Vtw);
    attn_f16<<<512, 256, 0, stream>>>(Qh, Kh, Vtw, out);
}

// Round 8
// 199.787 us; speedup vs baseline: 1.2296x; 1.2296x over previous
//
#include <hip/hip_runtime.h>
#include <math.h>

#define B_  2
#define S_  2048
#define D_  1024
#define H_  16
#define DH_ 64
#define M_  (B_ * S_)   // 4096

typedef _Float16 half_t;
typedef __attribute__((ext_vector_type(8))) _Float16 h8;
typedef __attribute__((ext_vector_type(4))) _Float16 h4;
typedef __attribute__((ext_vector_type(4))) float   f32x4;

#define LOG2E 1.44269504088896f

// async global->LDS, 16 B per lane (lane-contiguous dest, m104/m108)
__device__ __forceinline__ void gll16(const half_t* g, half_t* l) {
    __builtin_amdgcn_global_load_lds(
        (__attribute__((address_space(1))) const void*)g,
        (__attribute__((address_space(3))) void*)l, 16, 0, 0);
}

// ---------------------------------------------------------------------------
// Prepass (fused): blocks 0..2047 convert x fp32->fp16; blocks 2048..3583
// transpose W [k][n] fp32 -> Wt [n][k] fp16 (3 matrices).
// ---------------------------------------------------------------------------
__global__ __launch_bounds__(256) void prep_k(
    const float* __restrict__ x, half_t* __restrict__ xh,
    const float* __restrict__ Wq, const float* __restrict__ Wk,
    const float* __restrict__ Wv, half_t* __restrict__ Wt)
{
    const int bx = blockIdx.x;
    if (bx < 2048) {
        const size_t i = ((size_t)bx * 256 + threadIdx.x) * 8;
        const float4 a = *(const float4*)(x + i);
        const float4 b = *(const float4*)(x + i + 4);
        h8 o;
        o[0] = (half_t)a.x; o[1] = (half_t)a.y; o[2] = (half_t)a.z; o[3] = (half_t)a.w;
        o[4] = (half_t)b.x; o[5] = (half_t)b.y; o[6] = (half_t)b.z; o[7] = (half_t)b.w;
        *(h8*)(xh + i) = o;
    } else {
        const int gb    = bx - 2048;                 // 0..1535
        const int which = gb >> 9;
        const float* __restrict__ W = (which == 0) ? Wq : (which == 1) ? Wk : Wv;
        half_t* __restrict__ T = Wt + (size_t)which * D_ * D_;
        const int gw   = (gb & 511) * 4 + (threadIdx.x >> 6);   // 0..2047
        const int lane = threadIdx.x & 63;
        const int n    = (gw & 15) * 64 + lane;
        const int k0   = (gw >> 4) * 8;
        h8 o;
        #pragma unroll
        for (int t = 0; t < 8; ++t) o[t] = (half_t)W[(size_t)(k0 + t) * D_ + n];
        *(h8*)(T + (size_t)n * D_ + k0) = o;
    }
}

// ---------------------------------------------------------------------------
// Kernel 1: fused QKV projection.  128x128 tile, BK=64, global_load_lds into
// XOR-chunk-swizzled unpadded LDS.  XCD-aware 1D-swizzled grid.
// Epilogue: Q = tanh-GELU * log2e, K natural, V pre-transposed to Vt[bh][d][s].
// (unchanged from round 6 to isolate the attn change)
// ---------------------------------------------------------------------------
__global__ __launch_bounds__(256) void qkv_gemm_f16(
    const half_t* __restrict__ xh, const half_t* __restrict__ Wt,
    const float* __restrict__ bq, const float* __restrict__ bk,
    const float* __restrict__ bv,
    half_t* __restrict__ Qo, half_t* __restrict__ Ko, half_t* __restrict__ Vt)
{
    const int bi = blockIdx.x;                       // 0..767
    const int mt = (bi & 7) * 4 + ((bi >> 3) & 3);   // 0..31
    const int nt = bi >> 5;                          // 0..23
    const int m0 = mt * 128;
    const int n0g = nt * 128;
    const int which = n0g >> 10;
    const int n0    = n0g & 1023;
    const half_t* __restrict__ Wp  = Wt + (size_t)which * D_ * D_;
    const float* __restrict__ bias = (which == 0) ? bq : (which == 1) ? bk : bv;

    const int tid = threadIdx.x, lane = tid & 63, wave = tid >> 6;
    const int wm = (wave >> 1) * 64, wn = (wave & 1) * 64;
    const int ln = lane & 15, quad = lane >> 4;

    __shared__ __align__(16) half_t As[128 * 64];   // swizzled slots
    __shared__ __align__(16) half_t Bs[128 * 64];

    f32x4 acc[4][4];
    #pragma unroll
    for (int i = 0; i < 4; ++i)
        #pragma unroll
        for (int j = 0; j < 4; ++j) acc[i][j] = (f32x4){0.f, 0.f, 0.f, 0.f};

    for (int k0 = 0; k0 < D_; k0 += 64) {
        __syncthreads();
        #pragma unroll
        for (int l = 0; l < 4; ++l) {
            const int c  = tid + l * 256;
            const int r  = c >> 3, c0 = c & 7;
            const int cs = c0 ^ (r & 7);
            gll16(xh + (size_t)(m0 + r) * D_ + k0 + cs * 8, &As[c * 8]);
            gll16(Wp + (size_t)(n0 + r) * D_ + k0 + cs * 8, &Bs[c * 8]);
        }
        __syncthreads();

        #pragma unroll
        for (int kc = 0; kc < 2; ++kc) {
            h8 af[4], bf[4];
            #pragma unroll
            for (int i = 0; i < 4; ++i) {
                const int r = wm + i * 16 + ln;
                af[i] = *(const h8*)&As[r * 64 + (((kc << 2) + quad) ^ (r & 7)) * 8];
            }
            #pragma unroll
            for (int j = 0; j < 4; ++j) {
                const int r = wn + j * 16 + ln;
                bf[j] = *(const h8*)&Bs[r * 64 + (((kc << 2) + quad) ^ (r & 7)) * 8];
            }
            #pragma unroll
            for (int i = 0; i < 4; ++i)
                #pragma unroll
                for (int j = 0; j < 4; ++j)
                    acc[i][j] = __builtin_amdgcn_mfma_f32_16x16x32_f16(
                        af[i], bf[j], acc[i][j], 0, 0, 0);
        }
    }

    if (which == 2) {
        #pragma unroll
        for (int j = 0; j < 4; ++j) {
            const int col = n0 + wn + j * 16 + ln;
            const int h = col >> 6, d = col & 63;
            const float bb = bias[col];
            #pragma unroll
            for (int i = 0; i < 4; ++i) {
                const int sg = m0 + wm + i * 16 + quad * 4;
                const int b  = sg >> 11, srow = sg & 2047;
                h4 pv;
                #pragma unroll
                for (int r = 0; r < 4; ++r) pv[r] = (half_t)(acc[i][j][r] + bb);
                *(h4*)(Vt + (((size_t)(b * H_ + h) * DH_ + d) * S_ + srow)) = pv;
            }
        }
    } else {
        half_t* __restrict__ out = (which == 0) ? Qo : Ko;
        #pragma unroll
        for (int j = 0; j < 4; ++j) {
            const int col = n0 + wn + j * 16 + ln;
            const float bb = bias[col];
            #pragma unroll
            for (int i = 0; i < 4; ++i) {
                #pragma unroll
                for (int r = 0; r < 4; ++r) {
                    const int row = m0 + wm + i * 16 + quad * 4 + r;
                    float t = acc[i][j][r] + bb;
                    if (which == 0) {
                        const float u = t * fmaf(t * t, 0.0356774081f, 0.7978845608f);
                        const float e = __builtin_amdgcn_exp2f(u * -2.88539008178f);
                        t = t * __builtin_amdgcn_rcpf(1.0f + e) * LOG2E;
                    }
                    out[(size_t)row * D_ + col] = (half_t)t;
                }
            }
        }
    }
}

// ---------------------------------------------------------------------------
// Kernel 2: flash attention.  2-wave blocks (128 thr), 64 q-rows per block,
// each wave owns 32 q-rows as TWO q-groups -> every K/V fragment read feeds
// 2 MFMAs (round-6 arithmetic intensity) at round-5 grid size: 1024 blocks,
// 25.6 KB LDS, 88 VGPR -> ~6 blocks/CU (12 waves/CU) for latency hiding.
// K/V staged by global_load_lds, XOR-swizzled.  Logits pre-scaled by log2e
// (p = 2^x).  Conditional O/l rescale (ballot-uniform).  l via ones-MFMA.
// ---------------------------------------------------------------------------
__global__ __launch_bounds__(128) void attn_f16(
    const half_t* __restrict__ Q, const half_t* __restrict__ K,
    const half_t* __restrict__ Vt, float* __restrict__ out)
{
    const int tid  = threadIdx.x;
    const int lane = tid & 63;
    const int wave = tid >> 6;          // 0..1
    const int ln   = lane & 15;
    const int quad = lane >> 4;

    const int bi = blockIdx.x;                      // 0..1023
    const int bh = (bi & 7) * 4 + ((bi >> 3) & 3);  // 0..31 (XCD band)
    const int q0 = (bi >> 5) * 64;                  // 0..1984
    const int b  = bh >> 4;
    const int h  = bh & 15;

    const half_t* __restrict__ Qb  = Q  + (size_t)b * S_ * D_ + h * DH_;
    const half_t* __restrict__ Kb  = K  + (size_t)b * S_ * D_ + h * DH_;
    const half_t* __restrict__ Vtb = Vt + (size_t)bh * DH_ * S_;

    __shared__ __align__(16) half_t Ks[64 * 64];    // swizzled slots, 8 KB
    __shared__ __align__(16) half_t Vs[64 * 64];    // swizzled slots, 8 KB
    __shared__ __align__(16) half_t Ps[64][72];     // wave-private 32-row bands

    // ---- Q fragments, direct from global (one-time, 2 rows per lane) ----
    const int qra = q0 + wave * 32 + ln;
    const h8 qa0 = *(const h8*)(Qb + (size_t)qra * D_ + quad * 8);
    const h8 qa1 = *(const h8*)(Qb + (size_t)qra * D_ + 32 + quad * 8);
    const h8 qc0 = *(const h8*)(Qb + (size_t)(qra + 16) * D_ + quad * 8);
    const h8 qc1 = *(const h8*)(Qb + (size_t)(qra + 16) * D_ + 32 + quad * 8);

    h8 ones8;
    #pragma unroll
    for (int t = 0; t < 8; ++t) ones8[t] = (half_t)1.0f;

    f32x4 Oa[4], Ob[4];
    #pragma unroll
    for (int j = 0; j < 4; ++j) {
        Oa[j] = (f32x4){0.f, 0.f, 0.f, 0.f};
        Ob[j] = (f32x4){0.f, 0.f, 0.f, 0.f};
    }
    f32x4 la = (f32x4){0.f, 0.f, 0.f, 0.f};
    f32x4 lb = (f32x4){0.f, 0.f, 0.f, 0.f};
    float m_a = -INFINITY, m_b = -INFINITY;

    for (int k0 = 0; k0 < S_; k0 += 64) {
        // ---- stage K and V via async DMA, swizzled (4 chunks/thread each) ----
        __syncthreads();                   // previous tile fully consumed
        #pragma unroll
        for (int l = 0; l < 4; ++l) {
            const int c  = tid + l * 128;            // slot 0..511
            const int r  = c >> 3, c0 = c & 7;
            const int cs = c0 ^ (r & 7);
            gll16(Kb  + (size_t)(k0 + r) * D_ + cs * 8, &Ks[c * 8]);
            gll16(Vtb + (size_t)r * S_ + k0 + cs * 8,   &Vs[c * 8]);
        }
        __syncthreads();                   // DMA drained

        // ---- S^T = K Q^T for both q-groups ----
        f32x4 sa[4], sb[4];
        #pragma unroll
        for (int j = 0; j < 4; ++j) {
            const int rK = j * 16 + ln;
            const h8 ka0 = *(const h8*)&Ks[rK * 64 + ((quad)     ^ (rK & 7)) * 8];
            const h8 ka1 = *(const h8*)&Ks[rK * 64 + ((quad + 4) ^ (rK & 7)) * 8];
            f32x4 t = (f32x4){0.f, 0.f, 0.f, 0.f};
            t = __builtin_amdgcn_mfma_f32_16x16x32_f16(ka0, qa0, t, 0, 0, 0);
            t = __builtin_amdgcn_mfma_f32_16x16x32_f16(ka1, qa1, t, 0, 0, 0);
            sa[j] = t;
            f32x4 u = (f32x4){0.f, 0.f, 0.f, 0.f};
            u = __builtin_amdgcn_mfma_f32_16x16x32_f16(ka0, qc0, u, 0, 0, 0);
            u = __builtin_amdgcn_mfma_f32_16x16x32_f16(ka1, qc1, u, 0, 0, 0);
            sb[j] = u;
        }

        // ---- online softmax (log2 domain), conditional rescale ----
        float mxa = sa[0][0], mxb = sb[0][0];
        #pragma unroll
        for (int j = 0; j < 4; ++j)
            #pragma unroll
            for (int r = 0; r < 4; ++r) {
                mxa = fmaxf(mxa, sa[j][r]);
                mxb = fmaxf(mxb, sb[j][r]);
            }
        mxa = fmaxf(mxa, __shfl_xor(mxa, 16, 64));
        mxa = fmaxf(mxa, __shfl_xor(mxa, 32, 64));
        mxb = fmaxf(mxb, __shfl_xor(mxb, 16, 64));
        mxb = fmaxf(mxb, __shfl_xor(mxb, 32, 64));

        if (__ballot(mxa > m_a || mxb > m_b)) {
            const float mna = fmaxf(m_a, mxa);
            const float mnb = fmaxf(m_b, mxb);
            const float ala = __builtin_amdgcn_exp2f(m_a - mna);
            const float alb = __builtin_amdgcn_exp2f(m_b - mnb);
            m_a = mna; m_b = mnb;
            float ra[4], rb[4];
            #pragma unroll
            for (int r = 0; r < 4; ++r) {
                ra[r] = __shfl(ala, quad * 4 + r, 64);
                rb[r] = __shfl(alb, quad * 4 + r, 64);
            }
            #pragma unroll
            for (int r = 0; r < 4; ++r) {
                la[r] *= ra[r]; lb[r] *= rb[r];
                #pragma unroll
                for (int j = 0; j < 4; ++j) { Oa[j][r] *= ra[r]; Ob[j][r] *= rb[r]; }
            }
        }

        // p = 2^(s - m), h4-packed b64 writes into wave-private bands
        #pragma unroll
        for (int j = 0; j < 4; ++j) {
            h4 pva, pvb;
            #pragma unroll
            for (int r = 0; r < 4; ++r) {
                pva[r] = (half_t)__builtin_amdgcn_exp2f(sa[j][r] - m_a);
                pvb[r] = (half_t)__builtin_amdgcn_exp2f(sb[j][r] - m_b);
            }
            *(h4*)&Ps[wave * 32 + ln][j * 16 + quad * 4]      = pva;
            *(h4*)&Ps[wave * 32 + 16 + ln][j * 16 + quad * 4] = pvb;
        }

        // ---- O += P V, l += P 1 (both q-groups share each V fragment) ----
        const h8 pa0 = *(const h8*)&Ps[wave * 32 + ln][quad * 8];
        const h8 pa1 = *(const h8*)&Ps[wave * 32 + ln][32 + quad * 8];
        const h8 pb0 = *(const h8*)&Ps[wave * 32 + 16 + ln][quad * 8];
        const h8 pb1 = *(const h8*)&Ps[wave * 32 + 16 + ln][32 + quad * 8];
        #pragma unroll
        for (int j = 0; j < 4; ++j) {
            const int rV = j * 16 + ln;
            const h8 vb0 = *(const h8*)&Vs[rV * 64 + ((quad)     ^ (rV & 7)) * 8];
            const h8 vb1 = *(const h8*)&Vs[rV * 64 + ((quad + 4) ^ (rV & 7)) * 8];
            Oa[j] = __builtin_amdgcn_mfma_f32_16x16x32_f16(pa0, vb0, Oa[j], 0, 0, 0);
            Oa[j] = __builtin_amdgcn_mfma_f32_16x16x32_f16(pa1, vb1, Oa[j], 0, 0, 0);
            Ob[j] = __builtin_amdgcn_mfma_f32_16x16x32_f16(pb0, vb0, Ob[j], 0, 0, 0);
            Ob[j] = __builtin_amdgcn_mfma_f32_16x16x32_f16(pb1, vb1, Ob[j], 0, 0, 0);
        }
        la = __builtin_amdgcn_mfma_f32_16x16x32_f16(pa0, ones8, la, 0, 0, 0);
        la = __builtin_amdgcn_mfma_f32_16x16x32_f16(pa1, ones8, la, 0, 0, 0);
        lb = __builtin_amdgcn_mfma_f32_16x16x32_f16(pb0, ones8, lb, 0, 0, 0);
        lb = __builtin_amdgcn_mfma_f32_16x16x32_f16(pb1, ones8, lb, 0, 0, 0);
    }

    // ---- epilogue: normalize, store fp32 ----
    #pragma unroll
    for (int r = 0; r < 4; ++r) {
        const float iva = 1.0f / la[r];
        const float ivb = 1.0f / lb[r];
        const int rowa = q0 + wave * 32 + quad * 4 + r;
        const int rowb = rowa + 16;
        #pragma unroll
        for (int j = 0; j < 4; ++j) {
            out[((size_t)b * S_ + rowa) * D_ + h * DH_ + j * 16 + ln] = Oa[j][r] * iva;
            out[((size_t)b * S_ + rowb) * D_ + h * DH_ + j * 16 + ln] = Ob[j][r] * ivb;
        }
    }
}

// ---------------------------------------------------------------------------
extern "C" void kernel_launch(void* const* d_in, const int* in_sizes, int n_in,
                              void* d_out, int out_size, void* d_ws, size_t ws_size,
                              hipStream_t stream) {
    const float* x  = (const float*)d_in[0];
    const float* Wq = (const float*)d_in[1];
    const float* bq = (const float*)d_in[2];
    const float* Wk = (const float*)d_in[3];
    const float* bk = (const float*)d_in[4];
    const float* Wv = (const float*)d_in[5];
    const float* bv = (const float*)d_in[6];
    float* out = (float*)d_out;

    const size_t nmd = (size_t)M_ * D_;   // 4M
    const size_t ndd = (size_t)D_ * D_;   // 1M
    half_t* xh  = (half_t*)d_ws;          // 4M halves
    half_t* Wt  = xh + nmd;               // 3M
    half_t* Qh  = Wt + 3 * ndd;           // 4M
    half_t* Kh  = Qh + nmd;               // 4M
    half_t* Vtw = Kh + nmd;               // 4M  (38 MB total)

    prep_k<<<2048 + 1536, 256, 0, stream>>>(x, xh, Wq, Wk, Wv, Wt);
    qkv_gemm_f16<<<768, 256, 0, stream>>>(xh, Wt, bq, bk, bv, Qh, Kh, Vtw);
    attn_f16<<<1024, 128, 0, stream>>>(Qh, Kh, Vtw, out);
}